// Round 10
// baseline (352.855 us; speedup 1.0000x reference)
//
#include <hip/hip_runtime.h>

#define EMBED 1024
#define NHEAD 16
#define HDIM  64
#define BATCH 2
#define SEQ   2048
#define MTOK  (BATCH * SEQ)   // 4096 tokens
#define QSCALE 0.1803368801f  // (1/sqrt(64)) * log2(e): softmax done in base 2

typedef __bf16 bf16x8 __attribute__((ext_vector_type(8)));
typedef float  f32x4  __attribute__((ext_vector_type(4)));

// round-half-up f32->bf16 (bias <= 2^-25, well under harness threshold)
__device__ __forceinline__ unsigned short f2bf(float f) {
  return (unsigned short)((__float_as_uint(f) + 0x8000u) >> 16);
}
// pack two f32 -> bf16x2 in one v_perm: low = bf(a), high = bf(b)
__device__ __forceinline__ unsigned int pkbf(float a, float b) {
  unsigned int ua = __float_as_uint(a) + 0x8000u;
  unsigned int ub = __float_as_uint(b) + 0x8000u;
  return __builtin_amdgcn_perm(ub, ua, 0x07060302u);
}

// async global->LDS, 16B/lane; LDS dest = wave-uniform base + lane*16
__device__ __forceinline__ void gload_lds16(const unsigned short* g, unsigned short* l) {
  __builtin_amdgcn_global_load_lds((__attribute__((address_space(1))) void*)g,
                                   (__attribute__((address_space(3))) void*)l, 16, 0, 0);
}

// key permutation for K staging: LDS row r holds key kperm(r) so that the QK
// output registers ARE the x32 PV A-fragment (keys quad*8..+7 per 32-block).
__device__ __forceinline__ int kperm(int r) {
  return (r & 32) | (((r >> 2) & 3) << 3) | (((r >> 4) & 1) << 2) | (r & 3);
}

// ---------------- prep: cast X -> bf16 + 4 weight transpose-casts + zero attn flags ---
__global__ __launch_bounds__(256)
void prep_k(const float* __restrict__ X, unsigned short* __restrict__ Xbf,
            const float* __restrict__ w0, const float* __restrict__ w1,
            const float* __restrict__ w2, const float* __restrict__ w3,
            unsigned short* __restrict__ t0, unsigned short* __restrict__ t1,
            unsigned short* __restrict__ t2, unsigned short* __restrict__ t3,
            unsigned int* __restrict__ flags) {
  const int id = blockIdx.x;
  if (id < 4096) {                          // cast: 1M uint2 = 4M floats
    if (id == 0) {                          // zero the 512 attn pair-flags
      flags[threadIdx.x] = 0;
      flags[threadIdx.x + 256] = 0;
    }
    int i = id * 256 + threadIdx.x;
    float4 f = reinterpret_cast<const float4*>(X)[i];
    reinterpret_cast<uint2*>(Xbf)[i] = make_uint2(pkbf(f.x, f.y), pkbf(f.z, f.w));
    return;
  }
  const int t = id - 4096;                  // 0..1023: 4 weights x 256 tiles
  const float* s; unsigned short* d;
  switch (t >> 8) {
    case 0: s = w0; d = t0; break;
    case 1: s = w1; d = t1; break;
    case 2: s = w2; d = t2; break;
    default: s = w3; d = t3; break;
  }
  const int tt = t & 255;
  const int k0 = (tt >> 4) * 64, n0 = (tt & 15) * 64;
  __shared__ unsigned short T[64][65];
  for (int i = threadIdx.x; i < 4096; i += 256) {
    int r = i >> 6, c = i & 63;             // read coalesced over n
    T[c][r] = f2bf(s[(size_t)(k0 + r) * EMBED + n0 + c]);
  }
  __syncthreads();
  for (int i = threadIdx.x; i < 4096; i += 256) {
    int r = i >> 6, c = i & 63;             // write coalesced over k
    d[(size_t)(n0 + r) * EMBED + k0 + c] = T[r][c];
  }
}

// ---------------- GEMM  C[M][N] = A[M][1024] * Bt[N][1024]^T ----------------
// (round-3 verbatim: 3-buffer counted-vmcnt pipeline; best-measured config)
template<int MODE, int BM>
__global__ void gemm_k(const unsigned short* __restrict__ A,
                       const unsigned short* __restrict__ Bt,
                       const float* __restrict__ b0, const float* __restrict__ b1,
                       const float* __restrict__ b2,
                       unsigned short* __restrict__ oQ, unsigned short* __restrict__ oK,
                       unsigned short* __restrict__ oV, float* __restrict__ oF) {
  constexpr int MI = BM / 32;               // 4 (MODE0) or 2 (MODE1)
  constexpr int NT = EMBED / 32;            // 32 K-tiles of BK=32
  constexpr int LPT = BM / 64 + 2;          // gloads/wave/tile: A(BM/64) + B(2)

  __shared__ unsigned short As[3][BM][32];
  __shared__ unsigned short Bs[3][128][32];

  const int tid = threadIdx.x, lane = tid & 63, wave = tid >> 6;
  const int lr = lane & 15, quad = lane >> 4;
  const int wm = (wave >> 1) * (BM / 2), wn = (wave & 1) * 64;
  const int row0 = blockIdx.x * BM, col0 = blockIdx.y * 128;   // row-fastest
  const int srow = lane >> 2, sc = lane & 3;          // stage: 16 rows x 4 chunks/instr
  const int scsw = (sc ^ ((srow >> 1) & 3)) * 8;      // pre-swizzled global chunk (stage)
  const int sw = (quad ^ ((lr >> 1) & 3)) * 8;        // swizzled LDS chunk (read)

  const f32x4 fz = {0.f, 0.f, 0.f, 0.f};
  f32x4 acc[MI][4];
#pragma unroll
  for (int i = 0; i < MI; ++i)
#pragma unroll
    for (int j = 0; j < 4; ++j) acc[i][j] = fz;

  auto stage = [&](int bufi, int tt) {
#pragma unroll
    for (int g = 0; g < BM / 64; ++g) {     // A: BM rows, 16 rows/instr/wave
      int rbase = wave * (BM / 4) + g * 16;
      gload_lds16(&A[(size_t)(row0 + rbase + srow) * EMBED + tt * 32 + scsw],
                  &As[bufi][rbase][0]);
    }
#pragma unroll
    for (int g = 0; g < 2; ++g) {           // B: 128 rows, 2 instrs/wave
      int rbase = wave * 32 + g * 16;
      gload_lds16(&Bt[(size_t)(col0 + rbase + srow) * EMBED + tt * 32 + scsw],
                  &Bs[bufi][rbase][0]);
    }
  };

  // prologue: 2 tiles in flight before first wait
  stage(0, 0);
  stage(1, 1);

  int buf = 0, sb = 2;
  for (int t = 0; t < NT; ++t) {
    // wait for ONLY the tile about to be consumed; keep the rest in flight.
    if (t < NT - 1)
      asm volatile("s_waitcnt vmcnt(%0)" :: "n"(LPT) : "memory");
    else
      asm volatile("s_waitcnt vmcnt(0)" ::: "memory");
    __builtin_amdgcn_s_barrier();           // all waves' tile-t loads landed

    bf16x8 af[MI], bv[4];
#pragma unroll
    for (int i = 0; i < MI; ++i)
      af[i] = *reinterpret_cast<const bf16x8*>(&As[buf][wm + i * 16 + lr][sw]);
#pragma unroll
    for (int j = 0; j < 4; ++j)
      bv[j] = *reinterpret_cast<const bf16x8*>(&Bs[buf][wn + j * 16 + lr][sw]);

    __builtin_amdgcn_s_setprio(1);
#pragma unroll
    for (int i = 0; i < MI; ++i)
#pragma unroll
      for (int j = 0; j < 4; ++j)
        acc[i][j] = __builtin_amdgcn_mfma_f32_16x16x32_bf16(af[i], bv[j],
                                                            acc[i][j], 0, 0, 0);
    __builtin_amdgcn_s_setprio(0);

    if (t + 2 < NT) stage(sb, t + 2);       // overwrites buffer read at t-1
    buf = (buf == 2) ? 0 : buf + 1;
    sb  = (sb  == 2) ? 0 : sb  + 1;
  }

#pragma unroll
  for (int i = 0; i < MI; ++i) {
#pragma unroll
    for (int j = 0; j < 4; ++j) {
      const int col = col0 + wn + j * 16 + lr;
      if (MODE == 1) {
        const float bb = b0[col];
#pragma unroll
        for (int r = 0; r < 4; ++r) {
          const int row = row0 + wm + i * 16 + quad * 4 + r;
          oF[((size_t)row << 10) + col] = acc[i][j][r] + bb;
        }
      } else {
        const int which = col >> 10, cn = col & 1023;   // wave-uniform
        const float bb = (which == 0 ? b0 : which == 1 ? b1 : b2)[cn];
        const float sscale = (which == 0) ? QSCALE : 1.0f;
        const int h = cn >> 6, dd = cn & 63;
#pragma unroll
        for (int r = 0; r < 4; ++r) {
          const int row = row0 + wm + i * 16 + quad * 4 + r;
          const int b = row >> 11, ss = row & (SEQ - 1);
          const float v = (acc[i][j][r] + bb) * sscale;
          if (which == 0) {
            oQ[((((size_t)b * NHEAD + h) * SEQ + ss) << 6) + dd] = f2bf(v);
          } else if (which == 1) {
            oK[((((size_t)b * NHEAD + h) * SEQ + ss) << 6) + dd] = f2bf(v);
          } else {
            oV[(((size_t)b * NHEAD + h) * HDIM + dd) * SEQ + ss] = f2bf(v);
          }
        }
      }
    }
  }
}

// ---------------- flash attention: KV-split (kh=2), in-register P, atomic combine -----
// Round-9b: identical to round 9 except the partial-O workspace index now
// includes the WAVE coordinate (R9's bug: 4 waves clobbered the same 2048-float
// region -> absmax 0.19). Layout: pO[block][wave*8 + g*4 + d][quad][lr][4].
__global__ __launch_bounds__(256, 4)
void attn_k(const unsigned short* __restrict__ Qb,   // [B][H][S][Dh], pre-scaled
            const unsigned short* __restrict__ Kb,   // [B][H][S][Dh]
            const unsigned short* __restrict__ Vt,   // [B][H][Dh][S]
            unsigned short* __restrict__ Ctx,        // [B][S][EMBED] bf16
            float* __restrict__ pO,                  // [512*2][8192] f32 partials
            float* __restrict__ pl,                  // [512*2][128] f32 partials
            unsigned int* __restrict__ flags) {      // [512]
  __shared__ unsigned short Ks[2][64][64];   // key-permuted rows
  __shared__ unsigned short Vs[2][64][64];
  __shared__ unsigned int who;
  const int tid = threadIdx.x, lane = tid & 63, wave = tid >> 6;
  const int lr = lane & 15, quad = lane >> 4;
  const int bh = blockIdx.x, qt = blockIdx.y, kh = blockIdx.z;
  const size_t base = (size_t)bh * SEQ * HDIM;
  const int srow = lane >> 3, sc = lane & 7;
  const int sw0 = (quad ^ (lr & 7)) * 8;
  const int sw1 = ((quad ^ 4) ^ (lr & 7)) * 8;
  const int lo = kh * 16, hi = lo + 16;

  // Q frags direct from global (B operand: n = q = lane&15) — R6-proven path
  bf16x8 qf[2][2];
#pragma unroll
  for (int g = 0; g < 2; ++g) {
    const unsigned short* qrow =
        &Qb[base + (size_t)(qt * 128 + wave * 32 + g * 16 + lr) * HDIM];
    qf[g][0] = *reinterpret_cast<const bf16x8*>(&qrow[quad * 8]);
    qf[g][1] = *reinterpret_cast<const bf16x8*>(&qrow[(quad ^ 4) * 8]);
  }

  // stage K/V tile 'lo' into buffer 0 (K rows key-permuted)
#pragma unroll
  for (int g = 0; g < 2; ++g) {
    int rbase = wave * 16 + g * 8;
    int row = rbase + srow;
    gload_lds16(&Kb[base + (size_t)(lo * 64 + kperm(row)) * HDIM + ((sc ^ (row & 7)) * 8)],
                &Ks[0][rbase][0]);
    gload_lds16(&Vt[base + (size_t)row * SEQ + lo * 64 + ((sc ^ (row & 7)) * 8)],
                &Vs[0][rbase][0]);
  }
  __syncthreads();

  float l_part[2] = {0.f, 0.f};             // per-lane l for q = wave*32+g*16+lr
  const f32x4 fz = {0.f, 0.f, 0.f, 0.f};
  f32x4 oacc[2][4];
#pragma unroll
  for (int g = 0; g < 2; ++g)
#pragma unroll
    for (int d = 0; d < 4; ++d) oacc[g][d] = fz;

  for (int kt = lo;;) {
    const int buf = kt & 1;

    // async prefetch of tile kt+1 into the other buffer BEFORE compute
    if (kt + 1 < hi) {
#pragma unroll
      for (int g = 0; g < 2; ++g) {
        int rbase = wave * 16 + g * 8;
        int row = rbase + srow;
        gload_lds16(&Kb[base + (size_t)((kt + 1) * 64 + kperm(row)) * HDIM + ((sc ^ (row & 7)) * 8)],
                    &Ks[buf ^ 1][rbase][0]);
        gload_lds16(&Vt[base + (size_t)row * SEQ + (kt + 1) * 64 + ((sc ^ (row & 7)) * 8)],
                    &Vs[buf ^ 1][rbase][0]);
      }
    }

    // S^T[key][q]: A = permuted K rows, B = Q
    f32x4 sc4[2][4];
#pragma unroll
    for (int nt = 0; nt < 4; ++nt) {
      bf16x8 kf0 = *reinterpret_cast<const bf16x8*>(&Ks[buf][nt * 16 + lr][sw0]);
      bf16x8 kf1 = *reinterpret_cast<const bf16x8*>(&Ks[buf][nt * 16 + lr][sw1]);
#pragma unroll
      for (int g = 0; g < 2; ++g) {
        f32x4 a = __builtin_amdgcn_mfma_f32_16x16x32_bf16(kf0, qf[g][0], fz, 0, 0, 0);
        sc4[g][nt] = __builtin_amdgcn_mfma_f32_16x16x32_bf16(kf1, qf[g][1], a, 0, 0, 0);
      }
    }

    // P = exp2(S); accumulate l; pack in-register as x32 A-frags
    bf16x8 pf[2][2];
#pragma unroll
    for (int g = 0; g < 2; ++g)
#pragma unroll
      for (int b = 0; b < 2; ++b) {
        float e0 = __builtin_amdgcn_exp2f(sc4[g][2 * b][0]);
        float e1 = __builtin_amdgcn_exp2f(sc4[g][2 * b][1]);
        float e2 = __builtin_amdgcn_exp2f(sc4[g][2 * b][2]);
        float e3 = __builtin_amdgcn_exp2f(sc4[g][2 * b][3]);
        l_part[g] += (e0 + e1) + (e2 + e3);
        float o0 = __builtin_amdgcn_exp2f(sc4[g][2 * b + 1][0]);
        float o1 = __builtin_amdgcn_exp2f(sc4[g][2 * b + 1][1]);
        float o2 = __builtin_amdgcn_exp2f(sc4[g][2 * b + 1][2]);
        float o3 = __builtin_amdgcn_exp2f(sc4[g][2 * b + 1][3]);
        l_part[g] += (o0 + o1) + (o2 + o3);
        union { unsigned int u[4]; bf16x8 v; } pk;
        pk.u[0] = pkbf(e0, e1);
        pk.u[1] = pkbf(e2, e3);
        pk.u[2] = pkbf(o0, o1);
        pk.u[3] = pkbf(o2, o3);
        pf[g][b] = pk.v;
      }

    // PV: O[q][dh] += P x V (P from registers)
#pragma unroll
    for (int d = 0; d < 4; ++d) {
      bf16x8 vb0 = *reinterpret_cast<const bf16x8*>(&Vs[buf][d * 16 + lr][sw0]);
      bf16x8 vb1 = *reinterpret_cast<const bf16x8*>(&Vs[buf][d * 16 + lr][sw1]);
#pragma unroll
      for (int g = 0; g < 2; ++g) {
        oacc[g][d] = __builtin_amdgcn_mfma_f32_16x16x32_bf16(pf[g][0], vb0, oacc[g][d], 0, 0, 0);
        oacc[g][d] = __builtin_amdgcn_mfma_f32_16x16x32_bf16(pf[g][1], vb1, oacc[g][d], 0, 0, 0);
      }
    }

    if (++kt == hi) break;
    __syncthreads();
  }

  // reduce l across quads: every lane then holds l[q = wave*32+g*16+lr]
#pragma unroll
  for (int g = 0; g < 2; ++g) {
    l_part[g] += __shfl_xor(l_part[g], 16);
    l_part[g] += __shfl_xor(l_part[g], 32);
  }

  // ---- partial publish + atomic winner-combine ----
  const int pair = bh * 16 + qt;
  float* myO = pO + (size_t)(pair * 2 + kh) * 8192;
#pragma unroll
  for (int g = 0; g < 2; ++g)
#pragma unroll
    for (int d = 0; d < 4; ++d)
      *reinterpret_cast<f32x4*>(
          &myO[(((wave * 8 + g * 4 + d) * 4 + quad) * 16 + lr) * 4]) = oacc[g][d];
  if (quad == 0) {
#pragma unroll
    for (int g = 0; g < 2; ++g)
      pl[(pair * 2 + kh) * 128 + wave * 32 + g * 16 + lr] = l_part[g];
  }
  __threadfence();
  __syncthreads();
  if (tid == 0) who = atomicAdd(&flags[pair], 1u);
  __syncthreads();
  if (who == 0) return;                     // first finisher: partials published
  __threadfence();                          // acquire: see the other half's data

  const float* oO = pO + (size_t)(pair * 2 + (1 - kh)) * 8192;
  const float* ol = pl + (pair * 2 + (1 - kh)) * 128;
#pragma unroll
  for (int g = 0; g < 2; ++g) {
    l_part[g] += ol[wave * 32 + g * 16 + lr];
#pragma unroll
    for (int d = 0; d < 4; ++d)
      oacc[g][d] += *reinterpret_cast<const f32x4*>(
          &oO[(((wave * 8 + g * 4 + d) * 4 + quad) * 16 + lr) * 4]);
  }

  const int b = bh >> 4, h = bh & 15;
#pragma unroll
  for (int g = 0; g < 2; ++g) {
    float linv[4];
#pragma unroll
    for (int r = 0; r < 4; ++r) linv[r] = 1.0f / __shfl(l_part[g], quad * 4 + r);
#pragma unroll
    for (int d = 0; d < 4; ++d)
#pragma unroll
      for (int r = 0; r < 4; ++r) {
        const int q = qt * 128 + wave * 32 + g * 16 + quad * 4 + r;
        Ctx[(((size_t)b * SEQ + q) << 10) + h * 64 + d * 16 + lr] =
            f2bf(oacc[g][d][r] * linv[r]);
      }
  }
}

// ---------------- launch ----------------
extern "C" void kernel_launch(void* const* d_in, const int* in_sizes, int n_in,
                              void* d_out, int out_size, void* d_ws, size_t ws_size,
                              hipStream_t stream) {
  const float* X  = (const float*)d_in[0];
  const float* Wq = (const float*)d_in[1];
  const float* bq = (const float*)d_in[2];
  const float* Wk = (const float*)d_in[3];
  const float* bk = (const float*)d_in[4];
  const float* Wv = (const float*)d_in[5];
  const float* bv = (const float*)d_in[6];
  const float* Wo = (const float*)d_in[7];
  const float* bo = (const float*)d_in[8];

  unsigned short* ws = (unsigned short*)d_ws;
  const size_t M1 = (size_t)1024 * 1024;
  unsigned short* Xbf = ws;                 // 4M shorts
  unsigned short* WqT = ws + 4 * M1;        // weights n-major (q,k,v contiguous for fused B)
  unsigned short* WkT = ws + 5 * M1;
  unsigned short* WvT = ws + 6 * M1;
  unsigned short* WoT = ws + 7 * M1;
  unsigned short* Qb  = ws + 8 * M1;
  unsigned short* Kb  = ws + 12 * M1;
  unsigned short* Vt  = ws + 16 * M1;
  unsigned short* Ctx = ws + 20 * M1;       // ..48 MB
  float* pO          = (float*)(ws + 24 * M1);        // 32 MB: [1024][8192] f32
  float* pl          = (float*)(ws + 40 * M1);        // 512 KB
  unsigned int* flg  = (unsigned int*)(ws + 41 * M1); // 2 KB   (total ~82 MB)

  // prep: cast X (4096 blocks) + 4 weight transposes (1024 blocks) + zero flags
  prep_k<<<5120, 256, 0, stream>>>(X, Xbf, Wq, Wk, Wv, Wo, WqT, WkT, WvT, WoT, flg);

  // fused QKV projection: Bt = [WqT;WkT;WvT], N=3072; 128x128, counted-vmcnt pipeline
  gemm_k<0, 128><<<dim3(MTOK / 128, 3072 / 128), 256, 0, stream>>>(
      Xbf, WqT, bq, bk, bv, Qb, Kb, Vt, nullptr);

  // KV-split attention: grid (bh, qt, kh) = 32x16x2 = 1024 blocks = 4/CU
  attn_k<<<dim3(BATCH * NHEAD, SEQ / 128, 2), 256, 0, stream>>>(
      Qb, Kb, Vt, Ctx, pO, pl, flg);

  // output projection: 64x128, counted-vmcnt pipeline
  gemm_k<1, 64><<<dim3(MTOK / 64, EMBED / 128), 256, 0, stream>>>(
      Ctx, WoT, bo, nullptr, nullptr, nullptr, nullptr, nullptr, (float*)d_out);
}

// Round 11
// 187.787 us; speedup vs baseline: 1.8790x; 1.8790x over previous
//
#include <hip/hip_runtime.h>

#define EMBED 1024
#define NHEAD 16
#define HDIM  64
#define BATCH 2
#define SEQ   2048
#define MTOK  (BATCH * SEQ)   // 4096 tokens
#define QSCALE 0.1803368801f  // (1/sqrt(64)) * log2(e): softmax done in base 2

typedef __bf16 bf16x8 __attribute__((ext_vector_type(8)));
typedef float  f32x4  __attribute__((ext_vector_type(4)));

// round-half-up f32->bf16 (bias <= 2^-25, well under harness threshold)
__device__ __forceinline__ unsigned short f2bf(float f) {
  return (unsigned short)((__float_as_uint(f) + 0x8000u) >> 16);
}
// pack two f32 -> bf16x2 in one v_perm: low = bf(a), high = bf(b)
__device__ __forceinline__ unsigned int pkbf(float a, float b) {
  unsigned int ua = __float_as_uint(a) + 0x8000u;
  unsigned int ub = __float_as_uint(b) + 0x8000u;
  return __builtin_amdgcn_perm(ub, ua, 0x07060302u);
}

// async global->LDS, 16B/lane; LDS dest = wave-uniform base + lane*16
__device__ __forceinline__ void gload_lds16(const unsigned short* g, unsigned short* l) {
  __builtin_amdgcn_global_load_lds((__attribute__((address_space(1))) void*)g,
                                   (__attribute__((address_space(3))) void*)l, 16, 0, 0);
}

// key permutation for K staging: LDS row r holds key kperm(r) so that the QK
// output registers ARE the x32 PV A-fragment (keys quad*8..+7 per 32-block).
__device__ __forceinline__ int kperm(int r) {
  return (r & 32) | (((r >> 2) & 3) << 3) | (((r >> 4) & 1) << 2) | (r & 3);
}

// ---------------- prep: cast X -> bf16 (blocks 0..4095) + 4 weight transpose-casts ----------
__global__ __launch_bounds__(256)
void prep_k(const float* __restrict__ X, unsigned short* __restrict__ Xbf,
            const float* __restrict__ w0, const float* __restrict__ w1,
            const float* __restrict__ w2, const float* __restrict__ w3,
            unsigned short* __restrict__ t0, unsigned short* __restrict__ t1,
            unsigned short* __restrict__ t2, unsigned short* __restrict__ t3) {
  const int id = blockIdx.x;
  if (id < 4096) {                          // cast: 1M uint2 = 4M floats
    int i = id * 256 + threadIdx.x;
    float4 f = reinterpret_cast<const float4*>(X)[i];
    reinterpret_cast<uint2*>(Xbf)[i] = make_uint2(pkbf(f.x, f.y), pkbf(f.z, f.w));
    return;
  }
  const int t = id - 4096;                  // 0..1023: 4 weights x 256 tiles
  const float* s; unsigned short* d;
  switch (t >> 8) {
    case 0: s = w0; d = t0; break;
    case 1: s = w1; d = t1; break;
    case 2: s = w2; d = t2; break;
    default: s = w3; d = t3; break;
  }
  const int tt = t & 255;
  const int k0 = (tt >> 4) * 64, n0 = (tt & 15) * 64;
  __shared__ unsigned short T[64][65];
  for (int i = threadIdx.x; i < 4096; i += 256) {
    int r = i >> 6, c = i & 63;             // read coalesced over n
    T[c][r] = f2bf(s[(size_t)(k0 + r) * EMBED + n0 + c]);
  }
  __syncthreads();
  for (int i = threadIdx.x; i < 4096; i += 256) {
    int r = i >> 6, c = i & 63;             // write coalesced over k
    d[(size_t)(n0 + r) * EMBED + k0 + c] = T[r][c];
  }
}

// ---------------- GEMM  C[M][N] = A[M][1024] * Bt[N][1024]^T ----------------
// (round-3 verbatim: 3-buffer counted-vmcnt pipeline; best-measured config)
template<int MODE, int BM>
__global__ void gemm_k(const unsigned short* __restrict__ A,
                       const unsigned short* __restrict__ Bt,
                       const float* __restrict__ b0, const float* __restrict__ b1,
                       const float* __restrict__ b2,
                       unsigned short* __restrict__ oQ, unsigned short* __restrict__ oK,
                       unsigned short* __restrict__ oV, float* __restrict__ oF) {
  constexpr int MI = BM / 32;               // 4 (MODE0) or 2 (MODE1)
  constexpr int NT = EMBED / 32;            // 32 K-tiles of BK=32
  constexpr int LPT = BM / 64 + 2;          // gloads/wave/tile: A(BM/64) + B(2)

  __shared__ unsigned short As[3][BM][32];
  __shared__ unsigned short Bs[3][128][32];

  const int tid = threadIdx.x, lane = tid & 63, wave = tid >> 6;
  const int lr = lane & 15, quad = lane >> 4;
  const int wm = (wave >> 1) * (BM / 2), wn = (wave & 1) * 64;
  const int row0 = blockIdx.x * BM, col0 = blockIdx.y * 128;   // row-fastest
  const int srow = lane >> 2, sc = lane & 3;          // stage: 16 rows x 4 chunks/instr
  const int scsw = (sc ^ ((srow >> 1) & 3)) * 8;      // pre-swizzled global chunk (stage)
  const int sw = (quad ^ ((lr >> 1) & 3)) * 8;        // swizzled LDS chunk (read)

  const f32x4 fz = {0.f, 0.f, 0.f, 0.f};
  f32x4 acc[MI][4];
#pragma unroll
  for (int i = 0; i < MI; ++i)
#pragma unroll
    for (int j = 0; j < 4; ++j) acc[i][j] = fz;

  auto stage = [&](int bufi, int tt) {
#pragma unroll
    for (int g = 0; g < BM / 64; ++g) {     // A: BM rows, 16 rows/instr/wave
      int rbase = wave * (BM / 4) + g * 16;
      gload_lds16(&A[(size_t)(row0 + rbase + srow) * EMBED + tt * 32 + scsw],
                  &As[bufi][rbase][0]);
    }
#pragma unroll
    for (int g = 0; g < 2; ++g) {           // B: 128 rows, 2 instrs/wave
      int rbase = wave * 32 + g * 16;
      gload_lds16(&Bt[(size_t)(col0 + rbase + srow) * EMBED + tt * 32 + scsw],
                  &Bs[bufi][rbase][0]);
    }
  };

  // prologue: 2 tiles in flight before first wait
  stage(0, 0);
  stage(1, 1);

  int buf = 0, sb = 2;
  for (int t = 0; t < NT; ++t) {
    // wait for ONLY the tile about to be consumed; keep the rest in flight.
    if (t < NT - 1)
      asm volatile("s_waitcnt vmcnt(%0)" :: "n"(LPT) : "memory");
    else
      asm volatile("s_waitcnt vmcnt(0)" ::: "memory");
    __builtin_amdgcn_s_barrier();           // all waves' tile-t loads landed

    bf16x8 af[MI], bv[4];
#pragma unroll
    for (int i = 0; i < MI; ++i)
      af[i] = *reinterpret_cast<const bf16x8*>(&As[buf][wm + i * 16 + lr][sw]);
#pragma unroll
    for (int j = 0; j < 4; ++j)
      bv[j] = *reinterpret_cast<const bf16x8*>(&Bs[buf][wn + j * 16 + lr][sw]);

    __builtin_amdgcn_s_setprio(1);
#pragma unroll
    for (int i = 0; i < MI; ++i)
#pragma unroll
      for (int j = 0; j < 4; ++j)
        acc[i][j] = __builtin_amdgcn_mfma_f32_16x16x32_bf16(af[i], bv[j],
                                                            acc[i][j], 0, 0, 0);
    __builtin_amdgcn_s_setprio(0);

    if (t + 2 < NT) stage(sb, t + 2);       // overwrites buffer read at t-1
    buf = (buf == 2) ? 0 : buf + 1;
    sb  = (sb  == 2) ? 0 : sb  + 1;
  }

#pragma unroll
  for (int i = 0; i < MI; ++i) {
#pragma unroll
    for (int j = 0; j < 4; ++j) {
      const int col = col0 + wn + j * 16 + lr;
      if (MODE == 1) {
        const float bb = b0[col];
#pragma unroll
        for (int r = 0; r < 4; ++r) {
          const int row = row0 + wm + i * 16 + quad * 4 + r;
          oF[((size_t)row << 10) + col] = acc[i][j][r] + bb;
        }
      } else {
        const int which = col >> 10, cn = col & 1023;   // wave-uniform
        const float bb = (which == 0 ? b0 : which == 1 ? b1 : b2)[cn];
        const float sscale = (which == 0) ? QSCALE : 1.0f;
        const int h = cn >> 6, dd = cn & 63;
#pragma unroll
        for (int r = 0; r < 4; ++r) {
          const int row = row0 + wm + i * 16 + quad * 4 + r;
          const int b = row >> 11, ss = row & (SEQ - 1);
          const float v = (acc[i][j][r] + bb) * sscale;
          if (which == 0) {
            oQ[((((size_t)b * NHEAD + h) * SEQ + ss) << 6) + dd] = f2bf(v);
          } else if (which == 1) {
            oK[((((size_t)b * NHEAD + h) * SEQ + ss) << 6) + dd] = f2bf(v);
          } else {
            oV[(((size_t)b * NHEAD + h) * HDIM + dd) * SEQ + ss] = f2bf(v);
          }
        }
      }
    }
  }
}

// ---------------- flash attention: QBLK=128, in-register P, pipelined QK(t+1) ---------
// Round-11: 3-buffer K/V + one-tile-deep score pipeline. Per iter:
//   vmcnt(0)+barrier -> stage(t+2) -> QK(t+1)->scNxt -> softmax(scCur=t) -> PV(t).
// The 16 QK MFMAs issue first and retire in the background while the 32 exp2
// (trans pipe) + 16 pkbf (VALU) run -> the two busiest pipes overlap (T15).
// scCur/scNxt ping-pong via swapped lambda args (static indexing, rule #20);
// buffer roles rotate via scalar ints. Race-freedom: stage targets (t+2)%3,
// last read at iter t-1; this iter's vmcnt(0)-then-barrier guarantees all
// waves' tile-(t+1) loads landed before any QK read of that buffer.
// Same MFMAs / operand values / order per tile as R8 -> absmax must stay
// exactly 0.001480103. Q direct from global (bit-exact proven, R6/R10).
__global__ __launch_bounds__(256, 2)
void attn_k(const unsigned short* __restrict__ Qb,   // [B][H][S][Dh], pre-scaled
            const unsigned short* __restrict__ Kb,   // [B][H][S][Dh]
            const unsigned short* __restrict__ Vt,   // [B][H][Dh][S]
            unsigned short* __restrict__ Ctx) {      // [B][S][EMBED] bf16
  __shared__ unsigned short Ks[3][64][64];   // key-permuted rows
  __shared__ unsigned short Vs[3][64][64];
  const int tid = threadIdx.x, lane = tid & 63, wave = tid >> 6;
  const int lr = lane & 15, quad = lane >> 4;
  const int bh = blockIdx.x, qt = blockIdx.y;
  const size_t base = (size_t)bh * SEQ * HDIM;
  const int srow = lane >> 3, sc = lane & 7;
  const int sw0 = (quad ^ (lr & 7)) * 8;
  const int sw1 = ((quad ^ 4) ^ (lr & 7)) * 8;
  constexpr int NT = SEQ / 64;

  // Q frags direct from global (B operand: n = q = lane&15)
  bf16x8 qf[2][2];
#pragma unroll
  for (int g = 0; g < 2; ++g) {
    const unsigned short* qrow =
        &Qb[base + (size_t)(qt * 128 + wave * 32 + g * 16 + lr) * HDIM];
    qf[g][0] = *reinterpret_cast<const bf16x8*>(&qrow[quad * 8]);
    qf[g][1] = *reinterpret_cast<const bf16x8*>(&qrow[(quad ^ 4) * 8]);
  }

  auto stageKV = [&](int bufi, int kt) {
#pragma unroll
    for (int g = 0; g < 2; ++g) {
      int rbase = wave * 16 + g * 8;
      int row = rbase + srow;
      gload_lds16(&Kb[base + (size_t)(kt * 64 + kperm(row)) * HDIM + ((sc ^ (row & 7)) * 8)],
                  &Ks[bufi][rbase][0]);
      gload_lds16(&Vt[base + (size_t)row * SEQ + kt * 64 + ((sc ^ (row & 7)) * 8)],
                  &Vs[bufi][rbase][0]);
    }
  };

  const f32x4 fz = {0.f, 0.f, 0.f, 0.f};
  auto qk = [&](int bufi, f32x4 (&sco)[2][4]) {
#pragma unroll
    for (int nt = 0; nt < 4; ++nt) {
      bf16x8 kf0 = *reinterpret_cast<const bf16x8*>(&Ks[bufi][nt * 16 + lr][sw0]);
      bf16x8 kf1 = *reinterpret_cast<const bf16x8*>(&Ks[bufi][nt * 16 + lr][sw1]);
#pragma unroll
      for (int g = 0; g < 2; ++g) {
        f32x4 a = __builtin_amdgcn_mfma_f32_16x16x32_bf16(kf0, qf[g][0], fz, 0, 0, 0);
        sco[g][nt] = __builtin_amdgcn_mfma_f32_16x16x32_bf16(kf1, qf[g][1], a, 0, 0, 0);
      }
    }
  };

  float l_part[2] = {0.f, 0.f};
  f32x4 oacc[2][4];
#pragma unroll
  for (int g = 0; g < 2; ++g)
#pragma unroll
    for (int d = 0; d < 4; ++d) oacc[g][d] = fz;

  // prologue: tiles 0,1 staged; QK(0) -> scA
  stageKV(0, 0);
  stageKV(1, 1);
  asm volatile("s_waitcnt vmcnt(4)" ::: "memory");   // own tile-0 loads done
  __builtin_amdgcn_s_barrier();                      // all waves' tile-0 done
  f32x4 scA[2][4], scB[2][4];
  qk(0, scA);

  // body: softmax+PV of tile kt (scores in sCur), QK of kt+1 -> sNxt
  auto body = [&](f32x4 (&sCur)[2][4], f32x4 (&sNxt)[2][4], int kt,
                  int bPV, int bQK, int bST) {
    asm volatile("s_waitcnt vmcnt(0)" ::: "memory"); // tile kt+1 landed (issued 1 iter ago)
    __builtin_amdgcn_s_barrier();                    // ... in ALL waves
    if (kt + 2 < NT) stageKV(bST, kt + 2);
    if (kt + 1 < NT) qk(bQK, sNxt);                  // MFMA pipe; retires in background

    // softmax(sCur) -> in-register x32 A-frags (trans+VALU; overlaps QK above)
    bf16x8 pf[2][2];
#pragma unroll
    for (int g = 0; g < 2; ++g)
#pragma unroll
      for (int b = 0; b < 2; ++b) {
        float e0 = __builtin_amdgcn_exp2f(sCur[g][2 * b][0]);
        float e1 = __builtin_amdgcn_exp2f(sCur[g][2 * b][1]);
        float e2 = __builtin_amdgcn_exp2f(sCur[g][2 * b][2]);
        float e3 = __builtin_amdgcn_exp2f(sCur[g][2 * b][3]);
        l_part[g] += (e0 + e1) + (e2 + e3);
        float o0 = __builtin_amdgcn_exp2f(sCur[g][2 * b + 1][0]);
        float o1 = __builtin_amdgcn_exp2f(sCur[g][2 * b + 1][1]);
        float o2 = __builtin_amdgcn_exp2f(sCur[g][2 * b + 1][2]);
        float o3 = __builtin_amdgcn_exp2f(sCur[g][2 * b + 1][3]);
        l_part[g] += (o0 + o1) + (o2 + o3);
        union { unsigned int u[4]; bf16x8 v; } pk;
        pk.u[0] = pkbf(e0, e1);
        pk.u[1] = pkbf(e2, e3);
        pk.u[2] = pkbf(o0, o1);
        pk.u[3] = pkbf(o2, o3);
        pf[g][b] = pk.v;
      }

    // PV: O += P x V (P from registers, V from Vs[bPV])
#pragma unroll
    for (int d = 0; d < 4; ++d) {
      bf16x8 vb0 = *reinterpret_cast<const bf16x8*>(&Vs[bPV][d * 16 + lr][sw0]);
      bf16x8 vb1 = *reinterpret_cast<const bf16x8*>(&Vs[bPV][d * 16 + lr][sw1]);
#pragma unroll
      for (int g = 0; g < 2; ++g) {
        oacc[g][d] = __builtin_amdgcn_mfma_f32_16x16x32_bf16(pf[g][0], vb0, oacc[g][d], 0, 0, 0);
        oacc[g][d] = __builtin_amdgcn_mfma_f32_16x16x32_bf16(pf[g][1], vb1, oacc[g][d], 0, 0, 0);
      }
    }
  };

  // main loop, unrolled by 2 for static scA/scB ping-pong; buffers rotate u,v,w
  int u = 0, v = 1, w = 2;
  for (int kt = 0; kt < NT; kt += 2) {
    body(scA, scB, kt,     u, v, w);   // PV tile kt   from u; QK kt+1 from v; stage kt+2 -> w
    body(scB, scA, kt + 1, v, w, u);   // PV tile kt+1 from v; QK kt+2 from w; stage kt+3 -> u
    int t0 = u; u = w; w = v; v = t0;  // roles advanced by 2
  }

  // finalize l: quads covered disjoint key sets
#pragma unroll
  for (int g = 0; g < 2; ++g) {
    l_part[g] += __shfl_xor(l_part[g], 16);
    l_part[g] += __shfl_xor(l_part[g], 32);
  }

  const int b = bh >> 4, h = bh & 15;
#pragma unroll
  for (int g = 0; g < 2; ++g) {
    float linv[4];
#pragma unroll
    for (int r = 0; r < 4; ++r) linv[r] = 1.0f / __shfl(l_part[g], quad * 4 + r);
#pragma unroll
    for (int d = 0; d < 4; ++d)
#pragma unroll
      for (int r = 0; r < 4; ++r) {
        const int q = qt * 128 + wave * 32 + g * 16 + quad * 4 + r;
        Ctx[(((size_t)b * SEQ + q) << 10) + h * 64 + d * 16 + lr] =
            f2bf(oacc[g][d][r] * linv[r]);
      }
  }
}

// ---------------- launch ----------------
extern "C" void kernel_launch(void* const* d_in, const int* in_sizes, int n_in,
                              void* d_out, int out_size, void* d_ws, size_t ws_size,
                              hipStream_t stream) {
  const float* X  = (const float*)d_in[0];
  const float* Wq = (const float*)d_in[1];
  const float* bq = (const float*)d_in[2];
  const float* Wk = (const float*)d_in[3];
  const float* bk = (const float*)d_in[4];
  const float* Wv = (const float*)d_in[5];
  const float* bv = (const float*)d_in[6];
  const float* Wo = (const float*)d_in[7];
  const float* bo = (const float*)d_in[8];

  unsigned short* ws = (unsigned short*)d_ws;
  const size_t M1 = (size_t)1024 * 1024;
  unsigned short* Xbf = ws;                 // 4M shorts
  unsigned short* WqT = ws + 4 * M1;        // weights n-major (q,k,v contiguous for fused B)
  unsigned short* WkT = ws + 5 * M1;
  unsigned short* WvT = ws + 6 * M1;
  unsigned short* WoT = ws + 7 * M1;
  unsigned short* Qb  = ws + 8 * M1;
  unsigned short* Kb  = ws + 12 * M1;
  unsigned short* Vt  = ws + 16 * M1;
  unsigned short* Ctx = ws + 20 * M1;       // 48 MB total

  // prep: cast X (4096 blocks) + 4 weight transposes (1024 blocks)
  prep_k<<<5120, 256, 0, stream>>>(X, Xbf, Wq, Wk, Wv, Wo, WqT, WkT, WvT, WoT);

  // fused QKV projection: Bt = [WqT;WkT;WvT], N=3072; 128x128, counted-vmcnt pipeline
  gemm_k<0, 128><<<dim3(MTOK / 128, 3072 / 128), 256, 0, stream>>>(
      Xbf, WqT, bq, bk, bv, Qb, Kb, Vt, nullptr);

  // grid x = bh for XCD-pinned K/V L2 residency; QBLK=128, pipelined
  attn_k<<<dim3(BATCH * NHEAD, SEQ / 128), 256, 0, stream>>>(Qb, Kb, Vt, Ctx);

  // output projection: 64x128, counted-vmcnt pipeline
  gemm_k<1, 64><<<dim3(MTOK / 64, EMBED / 128), 256, 0, stream>>>(
      Ctx, WoT, bo, nullptr, nullptr, nullptr, nullptr, nullptr, (float*)d_out);
}